// Round 5
// baseline (195.284 us; speedup 1.0000x reference)
//
#include <hip/hip_runtime.h>
#include <hip/hip_bf16.h>
#include <float.h>
#include <math.h>

#define N_NODES 1024
#define N_EDGES 524288
#define IN_C    64
#define HID_C   128
#define OUT_C   512
#define MLP_H   64
#define ADJ_WORDS 32   // 1024 bits per dst row
#define KSPLIT  4
#define KCHUNK  (N_NODES / KSPLIT)  // 256

typedef __attribute__((ext_vector_type(8))) short short8;
typedef __attribute__((ext_vector_type(4))) float f32x4;

static __device__ __forceinline__ unsigned short f2bf(float f) {
    __hip_bfloat16 h = __float2bfloat16(f);
    return __builtin_bit_cast(unsigned short, h);
}

// pack fp32 W[64][C] into bf16 MFMA B-fragments: Wpk[nt][kf][lane][8]
// lane l of n-tile nt, k-frag kf supplies W[kf*32 + (l>>4)*8 + e][nt*16 + (l&15)]
static __device__ __forceinline__ void pack_w_one(
        const float* __restrict__ W, unsigned short* __restrict__ Wpk, int C, int idx) {
    int lane = idx & 63;
    int kf = (idx >> 6) & 1;
    int nt = idx >> 7;
    int kbase = kf * 32 + (lane >> 4) * 8;
    int c = nt * 16 + (lane & 15);
#pragma unroll
    for (int e = 0; e < 8; ++e)
        Wpk[idx * 8 + e] = f2bf(W[(kbase + e) * C + c]);
}

// ---------------------------------------------------------------------------
// k_init: range-partitioned fused prologue (1 launch replaces 5).
//   blocks [0,128)   : zero adjacency bitmap
//   blocks [128,132) : pack W2 -> Wpk1 (1024 frag-lanes)
//   blocks [132,148) : pack W4 -> Wpk2 (4096 frag-lanes)
//   blocks [148,404) : xform1, 4 nodes/block: A1 = x@W1_top + b1 ; B1 = x@W1_bot
//   blocks [404,660) : out[c][o] = br[o]  (bias pre-init for atomic readout)
// ---------------------------------------------------------------------------
__global__ __launch_bounds__(256) void k_init(
        unsigned int* __restrict__ adj,
        const float* __restrict__ W2, unsigned short* __restrict__ Wpk1,
        const float* __restrict__ W4, unsigned short* __restrict__ Wpk2,
        const float* __restrict__ x, const float* __restrict__ W1,
        const float* __restrict__ b1,
        float* __restrict__ A1, float* __restrict__ B1,
        const float* __restrict__ br, float* __restrict__ out) {
    __shared__ float xs[4][IN_C];
    const int b = blockIdx.x, tid = threadIdx.x;
    if (b < 128) {
        adj[b * 256 + tid] = 0u;
        return;
    }
    if (b < 132) { pack_w_one(W2, Wpk1, HID_C, (b - 128) * 256 + tid); return; }
    if (b < 148) { pack_w_one(W4, Wpk2, OUT_C, (b - 132) * 256 + tid); return; }
    if (b < 404) {
        const int sub = tid >> 6, t = tid & 63;
        const int n = (b - 148) * 4 + sub;
        xs[sub][t] = x[n * IN_C + t];
        __syncthreads();
        float a = b1[t], bb = 0.f;
#pragma unroll
        for (int k = 0; k < IN_C; ++k) {
            float xv = xs[sub][k];
            a = fmaf(xv, W1[k * MLP_H + t], a);
            bb = fmaf(xv, W1[(IN_C + k) * MLP_H + t], bb);
        }
        A1[n * MLP_H + t] = a;
        B1[n * MLP_H + t] = bb;
        return;
    }
    // bias init of out (float4 granularity): 256 blocks x 256 thr = 65536 float4
    int i4 = (b - 404) * 256 + tid;
    ((float4*)out)[i4] = ((const float4*)br)[i4 & 127];
}

__global__ void k_build_adj(const int* __restrict__ ei, unsigned int* __restrict__ adj) {
    int e = blockIdx.x * blockDim.x + threadIdx.x;
    if (e >= N_EDGES) return;
    int src = ei[e];            // edge_index[0] = src
    int dst = ei[N_EDGES + e];  // edge_index[1] = dst
    atomicOr(&adj[dst * ADJ_WORDS + (src >> 5)], 1u << (src & 31));
}

// ---------------------------------------------------------------------------
// fused edge-MLP second layer + segment-max via MFMA bf16, cooperative build.
// One block (4 waves) per dst node. Per batch of BATCH edge-tiles: each wave
// builds BATCH/4 tiles' bf16 A-fragments (z = relu(A[dst]+B[src])) into LDS
// (double-buffered, MFMA fragment layout), then ALL waves consume all tiles
// with register-resident W-fragments. Tail padded with list[0] duplicates
// (max idempotent). FUSEX: conv1 keeps h-row in LDS and computes A2/B2
// in-block (xform2 fused; h1 never hits global memory).
// ---------------------------------------------------------------------------
template <int NTILES, int C_TOTAL, int BATCH, int MINW, bool FUSEX>
__global__ __launch_bounds__(256, MINW) void k_conv_mfma(
        const unsigned int* __restrict__ adj,
        const float* __restrict__ Anode, const float* __restrict__ Bnode,
        const unsigned short* __restrict__ Wpk, const float* __restrict__ bias_g,
        float* __restrict__ outv,
        const float* __restrict__ W3, const float* __restrict__ b3,
        float* __restrict__ A2out, float* __restrict__ B2out) {
    __shared__ unsigned short list[N_NODES + 16];
    __shared__ short8 zbuf[2][BATCH][2][64];
    __shared__ float hrow[FUSEX ? HID_C : 1];
    __shared__ float xsum[FUSEX ? HID_C : 1];
    __shared__ int cnt;
    const int i = blockIdx.x;
    const int tid = threadIdx.x;
    const int lane = tid & 63;
    const int wave = tid >> 6;   // 0..3
    const int g = lane >> 4;     // lane group 0..3
    const int r = lane & 15;     // row within edge-tile / col within out-tile

    // wave 0: popcount prefix-scan compaction of adjacency row (no atomics)
    if (wave == 0) {
        unsigned int bits = (lane < ADJ_WORDS) ? adj[i * ADJ_WORDS + lane] : 0u;
        int c = __popc(bits);
        int pre = c;
#pragma unroll
        for (int d = 1; d < 64; d <<= 1) {
            int t = __shfl_up(pre, d);
            if (lane >= d) pre += t;
        }
        int total = __shfl(pre, 63);
        int pos = pre - c;  // exclusive start
        while (bits) {
            int b = __ffs(bits) - 1;
            bits &= bits - 1;
            list[pos++] = (unsigned short)(lane * 32 + b);
        }
        if (lane == 0) cnt = total;
    }
    __syncthreads();
    const int deg = cnt;
    const int padded = (deg + 15) & ~15;
    for (int p = deg + tid; p < padded; p += 256) list[p] = list[0];

    // W fragments in registers (static indices via full unroll)
    short8 wfr[NTILES][2];
#pragma unroll
    for (int n = 0; n < NTILES; ++n) {
        int nt = wave * NTILES + n;
#pragma unroll
        for (int kf = 0; kf < 2; ++kf)
            wfr[n][kf] = ((const short8*)Wpk)[(nt * 2 + kf) * 64 + lane];
    }

    // A[dst] slices this lane needs (fp32): k = g*8..g*8+7 and 32+g*8..+7
    const f32x4* Ap = (const f32x4*)(Anode + i * MLP_H);
    f32x4 a0 = Ap[g * 2], a1 = Ap[g * 2 + 1], a2 = Ap[8 + g * 2], a3 = Ap[9 + g * 2];

    float mx[NTILES];
#pragma unroll
    for (int n = 0; n < NTILES; ++n) mx[n] = -INFINITY;

    // build BATCH/4 edge-tiles per wave into zbuf[buf]
    auto build = [&](int buf, int base_tile, int ntl) {
#pragma unroll
        for (int u = 0; u < BATCH / 4; ++u) {
            int tt = u * 4 + wave;
            if (tt < ntl) {
                int j = list[(base_tile + tt) * 16 + r];
                const f32x4* Bp = (const f32x4*)(Bnode + (size_t)j * MLP_H);
                f32x4 b0 = Bp[g * 2], b1 = Bp[g * 2 + 1], b2 = Bp[8 + g * 2], b3v = Bp[9 + g * 2];
                f32x4 s0 = a0 + b0, s1 = a1 + b1, s2 = a2 + b2, s3 = a3 + b3v;
                short8 z0, z1;
#pragma unroll
                for (int e = 0; e < 4; ++e) {
                    z0[e]     = (short)f2bf(fmaxf(s0[e], 0.f));
                    z0[e + 4] = (short)f2bf(fmaxf(s1[e], 0.f));
                    z1[e]     = (short)f2bf(fmaxf(s2[e], 0.f));
                    z1[e + 4] = (short)f2bf(fmaxf(s3[e], 0.f));
                }
                zbuf[buf][tt][0][lane] = z0;
                zbuf[buf][tt][1][lane] = z1;
            }
        }
    };

    const int ntiles_e = padded >> 4;
    const f32x4 zero = {0.f, 0.f, 0.f, 0.f};

    __syncthreads();  // padding + list visible
    build(0, 0, min(BATCH, ntiles_e));
    __syncthreads();  // zbuf[0] ready

    int cur = 0;
    for (int b0 = 0; b0 < ntiles_e; b0 += BATCH) {
        int nb = min(BATCH, ntiles_e - b0);
        int nxt = b0 + BATCH;
        if (nxt < ntiles_e) build(cur ^ 1, nxt, min(BATCH, ntiles_e - nxt));
        for (int tt = 0; tt < nb; ++tt) {
            short8 z0 = zbuf[cur][tt][0][lane];
            short8 z1 = zbuf[cur][tt][1][lane];
#pragma unroll
            for (int n = 0; n < NTILES; ++n) {
                f32x4 acc = __builtin_amdgcn_mfma_f32_16x16x32_bf16(z0, wfr[n][0], zero, 0, 0, 0);
                acc = __builtin_amdgcn_mfma_f32_16x16x32_bf16(z1, wfr[n][1], acc, 0, 0, 0);
                // D col = lane&15 (verified layout); rows are max-reduced away
                mx[n] = fmaxf(mx[n], fmaxf(fmaxf(acc[0], acc[1]), fmaxf(acc[2], acc[3])));
            }
        }
        __syncthreads();
        cur ^= 1;
    }

    // combine partial maxes across the 4 lane-groups (same col = lane&15)
#pragma unroll
    for (int n = 0; n < NTILES; ++n) {
        mx[n] = fmaxf(mx[n], __shfl_xor(mx[n], 16));
        mx[n] = fmaxf(mx[n], __shfl_xor(mx[n], 32));
    }
    if (lane < 16) {
#pragma unroll
        for (int n = 0; n < NTILES; ++n) {
            int c = (wave * NTILES + n) * 16 + lane;
            float hv = (deg == 0) ? 0.f : mx[n] + bias_g[c];
            if constexpr (FUSEX) hrow[c] = hv;
            else                 outv[i * C_TOTAL + c] = hv;
        }
    }

    if constexpr (FUSEX) {
        // fused xform2: A2[i] = hrow @ W3[0:128] + b3 ; B2[i] = hrow @ W3[128:256]
        // W3 is [256][64]; thread (c, half, ksel) does a 64-long k-slice.
        __syncthreads();
        const int c = tid & 63;
        const int half = (tid >> 6) & 1;
        const int ksel = tid >> 7;
        const float* wp = W3 + (half * 128 + ksel * 64) * MLP_H + c;
        float s = 0.f;
#pragma unroll
        for (int k = 0; k < 64; ++k)
            s = fmaf(hrow[ksel * 64 + k], wp[k * MLP_H], s);
        if (ksel) xsum[half * 64 + c] = s;
        __syncthreads();
        if (!ksel) {
            s += xsum[half * 64 + c];
            if (half == 0) A2out[i * MLP_H + c] = s + b3[c];
            else           B2out[i * MLP_H + c] = s;
        }
    }
}

// ---------------------------------------------------------------------------
// readout split-K: atomicAdd partial tiles into bias-pre-initialized out.
// out[c][o] (+)= sum_{n in chunk} h2[n][c] * Wr[n][o]
// ---------------------------------------------------------------------------
__global__ __launch_bounds__(256) void k_readout_part(
        const float* __restrict__ h2, const float* __restrict__ Wr,
        float* __restrict__ out) {
    __shared__ float As[64][64];
    __shared__ float Bs[64][64];
    const int bid = blockIdx.x;
    const int kc = bid >> 6;
    const int c0 = ((bid >> 3) & 7) * 64;
    const int o0 = (bid & 7) * 64;
    const int k0 = kc * KCHUNK;
    const int tid = threadIdx.x;
    const int tx = tid & 15, ty = tid >> 4;
    float acc[4][4] = {};
    for (int ks = 0; ks < KCHUNK; ks += 64) {
        for (int s = tid; s < 1024; s += 256) {
            int rr = s >> 4;
            int cq = (s & 15) * 4;
            *(float4*)&As[rr][cq] = *(const float4*)&h2[(k0 + ks + rr) * OUT_C + c0 + cq];
            *(float4*)&Bs[rr][cq] = *(const float4*)&Wr[(k0 + ks + rr) * OUT_C + o0 + cq];
        }
        __syncthreads();
#pragma unroll 16
        for (int kk = 0; kk < 64; ++kk) {
            float4 a = *(float4*)&As[kk][ty * 4];
            float4 b = *(float4*)&Bs[kk][tx * 4];
            acc[0][0] = fmaf(a.x, b.x, acc[0][0]); acc[0][1] = fmaf(a.x, b.y, acc[0][1]);
            acc[0][2] = fmaf(a.x, b.z, acc[0][2]); acc[0][3] = fmaf(a.x, b.w, acc[0][3]);
            acc[1][0] = fmaf(a.y, b.x, acc[1][0]); acc[1][1] = fmaf(a.y, b.y, acc[1][1]);
            acc[1][2] = fmaf(a.y, b.z, acc[1][2]); acc[1][3] = fmaf(a.y, b.w, acc[1][3]);
            acc[2][0] = fmaf(a.z, b.x, acc[2][0]); acc[2][1] = fmaf(a.z, b.y, acc[2][1]);
            acc[2][2] = fmaf(a.z, b.z, acc[2][2]); acc[2][3] = fmaf(a.z, b.w, acc[2][3]);
            acc[3][0] = fmaf(a.w, b.x, acc[3][0]); acc[3][1] = fmaf(a.w, b.y, acc[3][1]);
            acc[3][2] = fmaf(a.w, b.z, acc[3][2]); acc[3][3] = fmaf(a.w, b.w, acc[3][3]);
        }
        __syncthreads();
    }
#pragma unroll
    for (int u = 0; u < 4; ++u)
#pragma unroll
        for (int v = 0; v < 4; ++v)
            atomicAdd(&out[(c0 + ty * 4 + u) * OUT_C + o0 + tx * 4 + v], acc[u][v]);
}

// ---------------------------------------------------------------------------
extern "C" void kernel_launch(void* const* d_in, const int* in_sizes, int n_in,
                              void* d_out, int out_size, void* d_ws, size_t ws_size,
                              hipStream_t stream) {
    const float* x  = (const float*)d_in[0];
    const int*   ei = (const int*)d_in[1];
    const float* W1 = (const float*)d_in[2];
    const float* b1 = (const float*)d_in[3];
    const float* W2 = (const float*)d_in[4];
    const float* b2 = (const float*)d_in[5];
    const float* W3 = (const float*)d_in[6];
    const float* b3 = (const float*)d_in[7];
    const float* W4 = (const float*)d_in[8];
    const float* b4 = (const float*)d_in[9];
    const float* Wr = (const float*)d_in[10];
    const float* br = (const float*)d_in[11];
    float* out = (float*)d_out;

    // workspace partition (256B-aligned)
    char* ws = (char*)d_ws;
    unsigned int* adj = (unsigned int*)ws;                  // 131072 B
    float* A1 = (float*)(ws + 131072);                      // 262144 B
    float* B1 = (float*)(ws + 393216);                      // 262144 B
    float* A2 = (float*)(ws + 655360);                      // 262144 B
    float* B2 = (float*)(ws + 917504);                      // 262144 B
    float* h2 = (float*)(ws + 1179648);                     // 2097152 B
    unsigned short* Wpk1 = (unsigned short*)(ws + 3276800); // 16384 B
    unsigned short* Wpk2 = (unsigned short*)(ws + 3293184); // 65536 B
    // total 3358720 B

    k_init<<<dim3(660), dim3(256), 0, stream>>>(adj, W2, Wpk1, W4, Wpk2,
                                                x, W1, b1, A1, B1, br, out);
    k_build_adj<<<dim3(N_EDGES / 256), dim3(256), 0, stream>>>(ei, adj);
    k_conv_mfma<2, HID_C, 4, 5, true><<<dim3(N_NODES), dim3(256), 0, stream>>>(
        adj, A1, B1, Wpk1, b2, nullptr, W3, b3, A2, B2);
    k_conv_mfma<8, OUT_C, 8, 4, false><<<dim3(N_NODES), dim3(256), 0, stream>>>(
        adj, A2, B2, Wpk2, b4, h2, nullptr, nullptr, nullptr, nullptr);
    k_readout_part<<<dim3(64 * KSPLIT), dim3(256), 0, stream>>>(h2, Wr, out);
}

// Round 6
// 174.591 us; speedup vs baseline: 1.1185x; 1.1185x over previous
//
#include <hip/hip_runtime.h>
#include <hip/hip_bf16.h>
#include <float.h>
#include <math.h>

#define N_NODES 1024
#define N_EDGES 524288
#define IN_C    64
#define HID_C   128
#define OUT_C   512
#define MLP_H   64
#define ADJ_WORDS 32   // 1024 bits per dst row
#define KSPLIT  16
#define KCHUNK  (N_NODES / KSPLIT)  // 64

typedef __attribute__((ext_vector_type(8))) short short8;
typedef __attribute__((ext_vector_type(4))) float f32x4;

static __device__ __forceinline__ unsigned short f2bf(float f) {
    __hip_bfloat16 h = __float2bfloat16(f);
    return __builtin_bit_cast(unsigned short, h);
}

// pack fp32 W[64][C] into bf16 MFMA B-fragments: Wpk[nt][kf][lane][8]
// lane l of n-tile nt, k-frag kf supplies W[kf*32 + (l>>4)*8 + e][nt*16 + (l&15)]
static __device__ __forceinline__ void pack_w_one(
        const float* __restrict__ W, unsigned short* __restrict__ Wpk, int C, int idx) {
    int lane = idx & 63;
    int kf = (idx >> 6) & 1;
    int nt = idx >> 7;
    int kbase = kf * 32 + (lane >> 4) * 8;
    int c = nt * 16 + (lane & 15);
#pragma unroll
    for (int e = 0; e < 8; ++e)
        Wpk[idx * 8 + e] = f2bf(W[(kbase + e) * C + c]);
}

// ---------------------------------------------------------------------------
// k_init: range-partitioned fused prologue (1 launch replaces 4).
//   blocks [0,128)   : zero adjacency bitmap
//   blocks [128,132) : pack W2 -> Wpk1 (1024 frag-lanes)
//   blocks [132,148) : pack W4 -> Wpk2 (4096 frag-lanes)
//   blocks [148,404) : xform1, 4 nodes/block: A1 = x@W1_top + b1 ; B1 = x@W1_bot
// ---------------------------------------------------------------------------
__global__ __launch_bounds__(256) void k_init(
        unsigned int* __restrict__ adj,
        const float* __restrict__ W2, unsigned short* __restrict__ Wpk1,
        const float* __restrict__ W4, unsigned short* __restrict__ Wpk2,
        const float* __restrict__ x, const float* __restrict__ W1,
        const float* __restrict__ b1,
        float* __restrict__ A1, float* __restrict__ B1) {
    __shared__ float xs[4][IN_C];
    const int b = blockIdx.x, tid = threadIdx.x;
    if (b < 128) {
        adj[b * 256 + tid] = 0u;
        return;
    }
    if (b < 132) { pack_w_one(W2, Wpk1, HID_C, (b - 128) * 256 + tid); return; }
    if (b < 148) { pack_w_one(W4, Wpk2, OUT_C, (b - 132) * 256 + tid); return; }
    const int sub = tid >> 6, t = tid & 63;
    const int n = (b - 148) * 4 + sub;
    xs[sub][t] = x[n * IN_C + t];
    __syncthreads();
    float a = b1[t], bb = 0.f;
#pragma unroll
    for (int k = 0; k < IN_C; ++k) {
        float xv = xs[sub][k];
        a = fmaf(xv, W1[k * MLP_H + t], a);
        bb = fmaf(xv, W1[(IN_C + k) * MLP_H + t], bb);
    }
    A1[n * MLP_H + t] = a;
    B1[n * MLP_H + t] = bb;
}

__global__ void k_build_adj(const int* __restrict__ ei, unsigned int* __restrict__ adj) {
    int e = blockIdx.x * blockDim.x + threadIdx.x;
    if (e >= N_EDGES) return;
    int src = ei[e];            // edge_index[0] = src
    int dst = ei[N_EDGES + e];  // edge_index[1] = dst
    atomicOr(&adj[dst * ADJ_WORDS + (src >> 5)], 1u << (src & 31));
}

// ---------------------------------------------------------------------------
// fused edge-MLP second layer + segment-max via MFMA bf16, cooperative build.
// One block (4 waves) per dst node. Per batch of BATCH edge-tiles: each wave
// builds BATCH/4 tiles' bf16 A-fragments (z = relu(A[dst]+B[src])) into LDS
// (double-buffered, MFMA fragment layout), then ALL waves consume all tiles
// with register-resident W-fragments. Tail padded with list[0] duplicates
// (max idempotent). FUSEX: conv1 keeps h-row in LDS and computes A2/B2
// in-block (xform2 fused; h1 never hits global memory).
// ---------------------------------------------------------------------------
template <int NTILES, int C_TOTAL, int BATCH, int MINW, bool FUSEX>
__global__ __launch_bounds__(256, MINW) void k_conv_mfma(
        const unsigned int* __restrict__ adj,
        const float* __restrict__ Anode, const float* __restrict__ Bnode,
        const unsigned short* __restrict__ Wpk, const float* __restrict__ bias_g,
        float* __restrict__ outv,
        const float* __restrict__ W3, const float* __restrict__ b3,
        float* __restrict__ A2out, float* __restrict__ B2out) {
    __shared__ unsigned short list[N_NODES + 16];
    __shared__ short8 zbuf[2][BATCH][2][64];
    __shared__ float hrow[FUSEX ? HID_C : 1];
    __shared__ float xsum[FUSEX ? HID_C : 1];
    __shared__ int cnt;
    const int i = blockIdx.x;
    const int tid = threadIdx.x;
    const int lane = tid & 63;
    const int wave = tid >> 6;   // 0..3
    const int g = lane >> 4;     // lane group 0..3
    const int r = lane & 15;     // row within edge-tile / col within out-tile

    // wave 0: popcount prefix-scan compaction of adjacency row (no atomics)
    if (wave == 0) {
        unsigned int bits = (lane < ADJ_WORDS) ? adj[i * ADJ_WORDS + lane] : 0u;
        int c = __popc(bits);
        int pre = c;
#pragma unroll
        for (int d = 1; d < 64; d <<= 1) {
            int t = __shfl_up(pre, d);
            if (lane >= d) pre += t;
        }
        int total = __shfl(pre, 63);
        int pos = pre - c;  // exclusive start
        while (bits) {
            int b = __ffs(bits) - 1;
            bits &= bits - 1;
            list[pos++] = (unsigned short)(lane * 32 + b);
        }
        if (lane == 0) cnt = total;
    }
    __syncthreads();
    const int deg = cnt;
    const int padded = (deg + 15) & ~15;
    for (int p = deg + tid; p < padded; p += 256) list[p] = list[0];

    // W fragments in registers (static indices via full unroll)
    short8 wfr[NTILES][2];
#pragma unroll
    for (int n = 0; n < NTILES; ++n) {
        int nt = wave * NTILES + n;
#pragma unroll
        for (int kf = 0; kf < 2; ++kf)
            wfr[n][kf] = ((const short8*)Wpk)[(nt * 2 + kf) * 64 + lane];
    }

    // A[dst] slices this lane needs (fp32): k = g*8..g*8+7 and 32+g*8..+7
    const f32x4* Ap = (const f32x4*)(Anode + i * MLP_H);
    f32x4 a0 = Ap[g * 2], a1 = Ap[g * 2 + 1], a2 = Ap[8 + g * 2], a3 = Ap[9 + g * 2];

    float mx[NTILES];
#pragma unroll
    for (int n = 0; n < NTILES; ++n) mx[n] = -INFINITY;

    // build BATCH/4 edge-tiles per wave into zbuf[buf]
    auto build = [&](int buf, int base_tile, int ntl) {
#pragma unroll
        for (int u = 0; u < BATCH / 4; ++u) {
            int tt = u * 4 + wave;
            if (tt < ntl) {
                int j = list[(base_tile + tt) * 16 + r];
                const f32x4* Bp = (const f32x4*)(Bnode + (size_t)j * MLP_H);
                f32x4 b0 = Bp[g * 2], b1 = Bp[g * 2 + 1], b2 = Bp[8 + g * 2], b3v = Bp[9 + g * 2];
                f32x4 s0 = a0 + b0, s1 = a1 + b1, s2 = a2 + b2, s3 = a3 + b3v;
                short8 z0, z1;
#pragma unroll
                for (int e = 0; e < 4; ++e) {
                    z0[e]     = (short)f2bf(fmaxf(s0[e], 0.f));
                    z0[e + 4] = (short)f2bf(fmaxf(s1[e], 0.f));
                    z1[e]     = (short)f2bf(fmaxf(s2[e], 0.f));
                    z1[e + 4] = (short)f2bf(fmaxf(s3[e], 0.f));
                }
                zbuf[buf][tt][0][lane] = z0;
                zbuf[buf][tt][1][lane] = z1;
            }
        }
    };

    const int ntiles_e = padded >> 4;
    const f32x4 zero = {0.f, 0.f, 0.f, 0.f};

    __syncthreads();  // padding + list visible
    build(0, 0, min(BATCH, ntiles_e));
    __syncthreads();  // zbuf[0] ready

    int cur = 0;
    for (int b0 = 0; b0 < ntiles_e; b0 += BATCH) {
        int nb = min(BATCH, ntiles_e - b0);
        int nxt = b0 + BATCH;
        if (nxt < ntiles_e) build(cur ^ 1, nxt, min(BATCH, ntiles_e - nxt));
        for (int tt = 0; tt < nb; ++tt) {
            short8 z0 = zbuf[cur][tt][0][lane];
            short8 z1 = zbuf[cur][tt][1][lane];
#pragma unroll
            for (int n = 0; n < NTILES; ++n) {
                f32x4 acc = __builtin_amdgcn_mfma_f32_16x16x32_bf16(z0, wfr[n][0], zero, 0, 0, 0);
                acc = __builtin_amdgcn_mfma_f32_16x16x32_bf16(z1, wfr[n][1], acc, 0, 0, 0);
                // D col = lane&15 (verified layout); rows are max-reduced away
                mx[n] = fmaxf(mx[n], fmaxf(fmaxf(acc[0], acc[1]), fmaxf(acc[2], acc[3])));
            }
        }
        __syncthreads();
        cur ^= 1;
    }

    // combine partial maxes across the 4 lane-groups (same col = lane&15)
#pragma unroll
    for (int n = 0; n < NTILES; ++n) {
        mx[n] = fmaxf(mx[n], __shfl_xor(mx[n], 16));
        mx[n] = fmaxf(mx[n], __shfl_xor(mx[n], 32));
    }
    if (lane < 16) {
#pragma unroll
        for (int n = 0; n < NTILES; ++n) {
            int c = (wave * NTILES + n) * 16 + lane;
            float hv = (deg == 0) ? 0.f : mx[n] + bias_g[c];
            if constexpr (FUSEX) hrow[c] = hv;
            else                 outv[i * C_TOTAL + c] = hv;
        }
    }

    if constexpr (FUSEX) {
        // fused xform2: A2[i] = hrow @ W3[0:128] + b3 ; B2[i] = hrow @ W3[128:256]
        // W3 is [256][64]; thread (c, half, ksel) does a 64-long k-slice.
        __syncthreads();
        const int c = tid & 63;
        const int half = (tid >> 6) & 1;
        const int ksel = tid >> 7;
        const float* wp = W3 + (half * 128 + ksel * 64) * MLP_H + c;
        float s = 0.f;
#pragma unroll
        for (int k = 0; k < 64; ++k)
            s = fmaf(hrow[ksel * 64 + k], wp[k * MLP_H], s);
        if (ksel) xsum[half * 64 + c] = s;
        __syncthreads();
        if (!ksel) {
            s += xsum[half * 64 + c];
            if (half == 0) A2out[i * MLP_H + c] = s + b3[c];
            else           B2out[i * MLP_H + c] = s;
        }
    }
}

// ---------------------------------------------------------------------------
// readout split-K partials: partial[kc][c][o] = sum_{n in 64-chunk} h2[n][c]*Wr[n][o]
// grid = 64 tiles * KSPLIT(16) = 1024 blocks (4/CU); single LDS stage, no k-loop.
// ---------------------------------------------------------------------------
__global__ __launch_bounds__(256) void k_readout_part(
        const float* __restrict__ h2, const float* __restrict__ Wr,
        float* __restrict__ partial) {
    __shared__ float As[64][64];
    __shared__ float Bs[64][64];
    const int bid = blockIdx.x;
    const int kc = bid >> 6;
    const int c0 = ((bid >> 3) & 7) * 64;
    const int o0 = (bid & 7) * 64;
    const int k0 = kc * KCHUNK;
    const int tid = threadIdx.x;
    const int tx = tid & 15, ty = tid >> 4;
    float acc[4][4] = {};
    for (int s = tid; s < 1024; s += 256) {
        int rr = s >> 4;
        int cq = (s & 15) * 4;
        *(float4*)&As[rr][cq] = *(const float4*)&h2[(k0 + rr) * OUT_C + c0 + cq];
        *(float4*)&Bs[rr][cq] = *(const float4*)&Wr[(k0 + rr) * OUT_C + o0 + cq];
    }
    __syncthreads();
#pragma unroll 16
    for (int kk = 0; kk < 64; ++kk) {
        float4 a = *(float4*)&As[kk][ty * 4];
        float4 b = *(float4*)&Bs[kk][tx * 4];
        acc[0][0] = fmaf(a.x, b.x, acc[0][0]); acc[0][1] = fmaf(a.x, b.y, acc[0][1]);
        acc[0][2] = fmaf(a.x, b.z, acc[0][2]); acc[0][3] = fmaf(a.x, b.w, acc[0][3]);
        acc[1][0] = fmaf(a.y, b.x, acc[1][0]); acc[1][1] = fmaf(a.y, b.y, acc[1][1]);
        acc[1][2] = fmaf(a.y, b.z, acc[1][2]); acc[1][3] = fmaf(a.y, b.w, acc[1][3]);
        acc[2][0] = fmaf(a.z, b.x, acc[2][0]); acc[2][1] = fmaf(a.z, b.y, acc[2][1]);
        acc[2][2] = fmaf(a.z, b.z, acc[2][2]); acc[2][3] = fmaf(a.z, b.w, acc[2][3]);
        acc[3][0] = fmaf(a.w, b.x, acc[3][0]); acc[3][1] = fmaf(a.w, b.y, acc[3][1]);
        acc[3][2] = fmaf(a.w, b.z, acc[3][2]); acc[3][3] = fmaf(a.w, b.w, acc[3][3]);
    }
    float* pb = partial + (size_t)kc * (OUT_C * OUT_C);
#pragma unroll
    for (int u = 0; u < 4; ++u) {
        float4 v = {acc[u][0], acc[u][1], acc[u][2], acc[u][3]};
        *(float4*)&pb[(c0 + ty * 4 + u) * OUT_C + o0 + tx * 4] = v;
    }
}

// reduce KSPLIT partials + bias -> out (65536 float4 outputs)
__global__ __launch_bounds__(256) void k_readout_reduce(
        const float* __restrict__ partial, const float* __restrict__ br,
        float* __restrict__ out) {
    int i = blockIdx.x * 256 + threadIdx.x;  // float4 index
    const float4* p4 = (const float4*)partial;
    float4 s = p4[i];
#pragma unroll
    for (int k = 1; k < KSPLIT; ++k) {
        float4 t = p4[i + k * 65536];
        s.x += t.x; s.y += t.y; s.z += t.z; s.w += t.w;
    }
    float4 b = ((const float4*)br)[i & 127];
    s.x += b.x; s.y += b.y; s.z += b.z; s.w += b.w;
    ((float4*)out)[i] = s;
}

// ---------------------------------------------------------------------------
extern "C" void kernel_launch(void* const* d_in, const int* in_sizes, int n_in,
                              void* d_out, int out_size, void* d_ws, size_t ws_size,
                              hipStream_t stream) {
    const float* x  = (const float*)d_in[0];
    const int*   ei = (const int*)d_in[1];
    const float* W1 = (const float*)d_in[2];
    const float* b1 = (const float*)d_in[3];
    const float* W2 = (const float*)d_in[4];
    const float* b2 = (const float*)d_in[5];
    const float* W3 = (const float*)d_in[6];
    const float* b3 = (const float*)d_in[7];
    const float* W4 = (const float*)d_in[8];
    const float* b4 = (const float*)d_in[9];
    const float* Wr = (const float*)d_in[10];
    const float* br = (const float*)d_in[11];
    float* out = (float*)d_out;

    // workspace partition (256B-aligned)
    char* ws = (char*)d_ws;
    unsigned int* adj = (unsigned int*)ws;                  // 131072 B
    float* A1 = (float*)(ws + 131072);                      // 262144 B
    float* B1 = (float*)(ws + 393216);                      // 262144 B
    float* A2 = (float*)(ws + 655360);                      // 262144 B
    float* B2 = (float*)(ws + 917504);                      // 262144 B
    float* h2 = (float*)(ws + 1179648);                     // 2097152 B
    unsigned short* Wpk1 = (unsigned short*)(ws + 3276800); // 16384 B
    unsigned short* Wpk2 = (unsigned short*)(ws + 3293184); // 65536 B
    float* partial = (float*)(ws + 3358720);                // 16777216 B (KSPLIT=16 x 1MB)
    // total 20135936 B

    k_init<<<dim3(404), dim3(256), 0, stream>>>(adj, W2, Wpk1, W4, Wpk2,
                                                x, W1, b1, A1, B1);
    k_build_adj<<<dim3(N_EDGES / 256), dim3(256), 0, stream>>>(ei, adj);
    k_conv_mfma<2, HID_C, 4, 5, true><<<dim3(N_NODES), dim3(256), 0, stream>>>(
        adj, A1, B1, Wpk1, b2, nullptr, W3, b3, A2, B2);
    k_conv_mfma<8, OUT_C, 8, 4, false><<<dim3(N_NODES), dim3(256), 0, stream>>>(
        adj, A2, B2, Wpk2, b4, h2, nullptr, nullptr, nullptr, nullptr);
    k_readout_part<<<dim3(64 * KSPLIT), dim3(256), 0, stream>>>(h2, Wr, partial);
    k_readout_reduce<<<dim3(256), dim3(256), 0, stream>>>(partial, br, out);
}

// Round 8
// 170.807 us; speedup vs baseline: 1.1433x; 1.0222x over previous
//
#include <hip/hip_runtime.h>
#include <hip/hip_bf16.h>
#include <float.h>
#include <math.h>

#define N_NODES 1024
#define N_EDGES 524288
#define IN_C    64
#define HID_C   128
#define OUT_C   512
#define MLP_H   64
#define ADJ_WORDS 32   // 1024 bits per dst row
#define KSPLIT  8
#define KCHUNK  (N_NODES / KSPLIT)  // 128

typedef __attribute__((ext_vector_type(8))) short short8;
typedef __attribute__((ext_vector_type(4))) float f32x4;

static __device__ __forceinline__ unsigned short f2bf(float f) {
    __hip_bfloat16 h = __float2bfloat16(f);
    return __builtin_bit_cast(unsigned short, h);
}

// pack fp32 W[64][C] into bf16 MFMA B-fragments: Wpk[nt][kf][lane][8]
// lane l of n-tile nt, k-frag kf supplies W[kf*32 + (l>>4)*8 + e][nt*16 + (l&15)]
static __device__ __forceinline__ void pack_w_one(
        const float* __restrict__ W, unsigned short* __restrict__ Wpk, int C, int idx) {
    int lane = idx & 63;
    int kf = (idx >> 6) & 1;
    int nt = idx >> 7;
    int kbase = kf * 32 + (lane >> 4) * 8;
    int c = nt * 16 + (lane & 15);
#pragma unroll
    for (int e = 0; e < 8; ++e)
        Wpk[idx * 8 + e] = f2bf(W[(kbase + e) * C + c]);
}

// ---------------------------------------------------------------------------
// k_init: range-partitioned fused prologue.
//   blocks [0,128)   : zero adjacency bitmap
//   blocks [128,132) : pack W2 -> Wpk1 (1024 frag-lanes)
//   blocks [132,148) : pack W4 -> Wpk2 (4096 frag-lanes)
//   blocks [148,404) : xform1, 4 nodes/block: A1 = x@W1_top + b1 ; B1 = x@W1_bot
// ---------------------------------------------------------------------------
__global__ __launch_bounds__(256) void k_init(
        unsigned int* __restrict__ adj,
        const float* __restrict__ W2, unsigned short* __restrict__ Wpk1,
        const float* __restrict__ W4, unsigned short* __restrict__ Wpk2,
        const float* __restrict__ x, const float* __restrict__ W1,
        const float* __restrict__ b1,
        float* __restrict__ A1, float* __restrict__ B1) {
    __shared__ float xs[4][IN_C];
    const int b = blockIdx.x, tid = threadIdx.x;
    if (b < 128) {
        adj[b * 256 + tid] = 0u;
        return;
    }
    if (b < 132) { pack_w_one(W2, Wpk1, HID_C, (b - 128) * 256 + tid); return; }
    if (b < 148) { pack_w_one(W4, Wpk2, OUT_C, (b - 132) * 256 + tid); return; }
    const int sub = tid >> 6, t = tid & 63;
    const int n = (b - 148) * 4 + sub;
    xs[sub][t] = x[n * IN_C + t];
    __syncthreads();
    float a = b1[t], bb = 0.f;
#pragma unroll
    for (int k = 0; k < IN_C; ++k) {
        float xv = xs[sub][k];
        a = fmaf(xv, W1[k * MLP_H + t], a);
        bb = fmaf(xv, W1[(IN_C + k) * MLP_H + t], bb);
    }
    A1[n * MLP_H + t] = a;
    B1[n * MLP_H + t] = bb;
}

__global__ void k_build_adj(const int* __restrict__ ei, unsigned int* __restrict__ adj) {
    int e = blockIdx.x * blockDim.x + threadIdx.x;
    if (e >= N_EDGES) return;
    int src = ei[e];            // edge_index[0] = src
    int dst = ei[N_EDGES + e];  // edge_index[1] = dst
    atomicOr(&adj[dst * ADJ_WORDS + (src >> 5)], 1u << (src & 31));
}

// ---------------------------------------------------------------------------
// fused edge-MLP second layer + segment-max via MFMA bf16, cooperative build.
// One block (4 waves) per dst node. Per batch of BATCH edge-tiles: each wave
// builds BATCH/4 tiles' bf16 A-fragments (z = relu(A[dst]+B[src])) into LDS
// (double-buffered, MFMA fragment layout), then ALL waves consume all tiles
// with register-resident W-fragments (setprio(1) around the MFMA cluster).
// Tail padded with list[0] duplicates (max idempotent). FUSEX: conv1 keeps
// h-row in LDS and computes A2/B2 in-block (xform2 fused).
// ---------------------------------------------------------------------------
template <int NTILES, int C_TOTAL, int BATCH, int MINW, bool FUSEX>
__global__ __launch_bounds__(256, MINW) void k_conv_mfma(
        const unsigned int* __restrict__ adj,
        const float* __restrict__ Anode, const float* __restrict__ Bnode,
        const unsigned short* __restrict__ Wpk, const float* __restrict__ bias_g,
        float* __restrict__ outv,
        const float* __restrict__ W3, const float* __restrict__ b3,
        float* __restrict__ A2out, float* __restrict__ B2out) {
    __shared__ unsigned short list[N_NODES + 16];
    __shared__ short8 zbuf[2][BATCH][2][64];
    __shared__ float hrow[FUSEX ? HID_C : 1];
    __shared__ float xsum[FUSEX ? HID_C : 1];
    __shared__ int cnt;
    const int i = blockIdx.x;
    const int tid = threadIdx.x;
    const int lane = tid & 63;
    const int wave = tid >> 6;   // 0..3
    const int g = lane >> 4;     // lane group 0..3
    const int r = lane & 15;     // row within edge-tile / col within out-tile

    // W fragments + A[dst] slices first: global-load latency hides under the
    // wave-0 compaction scan below.
    short8 wfr[NTILES][2];
#pragma unroll
    for (int n = 0; n < NTILES; ++n) {
        int nt = wave * NTILES + n;
#pragma unroll
        for (int kf = 0; kf < 2; ++kf)
            wfr[n][kf] = ((const short8*)Wpk)[(nt * 2 + kf) * 64 + lane];
    }
    const f32x4* Ap = (const f32x4*)(Anode + i * MLP_H);
    f32x4 a0 = Ap[g * 2], a1 = Ap[g * 2 + 1], a2 = Ap[8 + g * 2], a3 = Ap[9 + g * 2];

    // wave 0: popcount prefix-scan compaction of adjacency row (no atomics)
    if (wave == 0) {
        unsigned int bits = (lane < ADJ_WORDS) ? adj[i * ADJ_WORDS + lane] : 0u;
        int c = __popc(bits);
        int pre = c;
#pragma unroll
        for (int d = 1; d < 64; d <<= 1) {
            int t = __shfl_up(pre, d);
            if (lane >= d) pre += t;
        }
        int total = __shfl(pre, 63);
        int pos = pre - c;  // exclusive start
        while (bits) {
            int b = __ffs(bits) - 1;
            bits &= bits - 1;
            list[pos++] = (unsigned short)(lane * 32 + b);
        }
        if (lane == 0) cnt = total;
    }
    __syncthreads();
    const int deg = cnt;
    const int padded = (deg + 15) & ~15;
    for (int p = deg + tid; p < padded; p += 256) list[p] = list[0];

    float mx[NTILES];
#pragma unroll
    for (int n = 0; n < NTILES; ++n) mx[n] = -INFINITY;

    // build BATCH/4 edge-tiles per wave into zbuf[buf]
    auto build = [&](int buf, int base_tile, int ntl) {
#pragma unroll
        for (int u = 0; u < BATCH / 4; ++u) {
            int tt = u * 4 + wave;
            if (tt < ntl) {
                int j = list[(base_tile + tt) * 16 + r];
                const f32x4* Bp = (const f32x4*)(Bnode + (size_t)j * MLP_H);
                f32x4 b0 = Bp[g * 2], b1 = Bp[g * 2 + 1], b2 = Bp[8 + g * 2], b3v = Bp[9 + g * 2];
                f32x4 s0 = a0 + b0, s1 = a1 + b1, s2 = a2 + b2, s3 = a3 + b3v;
                short8 z0, z1;
#pragma unroll
                for (int e = 0; e < 4; ++e) {
                    z0[e]     = (short)f2bf(fmaxf(s0[e], 0.f));
                    z0[e + 4] = (short)f2bf(fmaxf(s1[e], 0.f));
                    z1[e]     = (short)f2bf(fmaxf(s2[e], 0.f));
                    z1[e + 4] = (short)f2bf(fmaxf(s3[e], 0.f));
                }
                zbuf[buf][tt][0][lane] = z0;
                zbuf[buf][tt][1][lane] = z1;
            }
        }
    };

    const int ntiles_e = padded >> 4;
    const f32x4 zero = {0.f, 0.f, 0.f, 0.f};

    __syncthreads();  // padding + list visible
    build(0, 0, min(BATCH, ntiles_e));
    __syncthreads();  // zbuf[0] ready

    int cur = 0;
    for (int b0 = 0; b0 < ntiles_e; b0 += BATCH) {
        int nb = min(BATCH, ntiles_e - b0);
        int nxt = b0 + BATCH;
        if (nxt < ntiles_e) build(cur ^ 1, nxt, min(BATCH, ntiles_e - nxt));
        __builtin_amdgcn_s_setprio(1);
        for (int tt = 0; tt < nb; ++tt) {
            short8 z0 = zbuf[cur][tt][0][lane];
            short8 z1 = zbuf[cur][tt][1][lane];
#pragma unroll
            for (int n = 0; n < NTILES; ++n) {
                f32x4 acc = __builtin_amdgcn_mfma_f32_16x16x32_bf16(z0, wfr[n][0], zero, 0, 0, 0);
                acc = __builtin_amdgcn_mfma_f32_16x16x32_bf16(z1, wfr[n][1], acc, 0, 0, 0);
                // D col = lane&15 (verified layout); rows are max-reduced away
                mx[n] = fmaxf(mx[n], fmaxf(fmaxf(acc[0], acc[1]), fmaxf(acc[2], acc[3])));
            }
        }
        __builtin_amdgcn_s_setprio(0);
        __syncthreads();
        cur ^= 1;
    }

    // combine partial maxes across the 4 lane-groups (same col = lane&15)
#pragma unroll
    for (int n = 0; n < NTILES; ++n) {
        mx[n] = fmaxf(mx[n], __shfl_xor(mx[n], 16));
        mx[n] = fmaxf(mx[n], __shfl_xor(mx[n], 32));
    }
    if (lane < 16) {
#pragma unroll
        for (int n = 0; n < NTILES; ++n) {
            int c = (wave * NTILES + n) * 16 + lane;
            float hv = (deg == 0) ? 0.f : mx[n] + bias_g[c];
            if constexpr (FUSEX) hrow[c] = hv;
            else                 outv[i * C_TOTAL + c] = hv;
        }
    }

    if constexpr (FUSEX) {
        // fused xform2: A2[i] = hrow @ W3[0:128] + b3 ; B2[i] = hrow @ W3[128:256]
        // W3 is [256][64]; thread (c, half, ksel) does a 64-long k-slice.
        __syncthreads();
        const int c = tid & 63;
        const int half = (tid >> 6) & 1;
        const int ksel = tid >> 7;
        const float* wp = W3 + (half * 128 + ksel * 64) * MLP_H + c;
        float s = 0.f;
#pragma unroll
        for (int k = 0; k < 64; ++k)
            s = fmaf(hrow[ksel * 64 + k], wp[k * MLP_H], s);
        if (ksel) xsum[half * 64 + c] = s;
        __syncthreads();
        if (!ksel) {
            s += xsum[half * 64 + c];
            if (half == 0) A2out[i * MLP_H + c] = s + b3[c];
            else           B2out[i * MLP_H + c] = s;
        }
    }
}

// ---------------------------------------------------------------------------
// readout split-K partials: partial[kc][c][o] = sum_{n in 128-chunk} h2[n][c]*Wr[n][o]
// grid = 64 tiles * KSPLIT(8) = 512 blocks (2/CU).
// ---------------------------------------------------------------------------
__global__ __launch_bounds__(256) void k_readout_part(
        const float* __restrict__ h2, const float* __restrict__ Wr,
        float* __restrict__ partial) {
    __shared__ float As[64][64];
    __shared__ float Bs[64][64];
    const int bid = blockIdx.x;
    const int kc = bid >> 6;
    const int c0 = ((bid >> 3) & 7) * 64;
    const int o0 = (bid & 7) * 64;
    const int k0 = kc * KCHUNK;
    const int tid = threadIdx.x;
    const int tx = tid & 15, ty = tid >> 4;
    float acc[4][4] = {};
    for (int ks = 0; ks < KCHUNK; ks += 64) {
        for (int s = tid; s < 1024; s += 256) {
            int rr = s >> 4;
            int cq = (s & 15) * 4;
            *(float4*)&As[rr][cq] = *(const float4*)&h2[(k0 + ks + rr) * OUT_C + c0 + cq];
            *(float4*)&Bs[rr][cq] = *(const float4*)&Wr[(k0 + ks + rr) * OUT_C + o0 + cq];
        }
        __syncthreads();
#pragma unroll 16
        for (int kk = 0; kk < 64; ++kk) {
            float4 a = *(float4*)&As[kk][ty * 4];
            float4 b = *(float4*)&Bs[kk][tx * 4];
            acc[0][0] = fmaf(a.x, b.x, acc[0][0]); acc[0][1] = fmaf(a.x, b.y, acc[0][1]);
            acc[0][2] = fmaf(a.x, b.z, acc[0][2]); acc[0][3] = fmaf(a.x, b.w, acc[0][3]);
            acc[1][0] = fmaf(a.y, b.x, acc[1][0]); acc[1][1] = fmaf(a.y, b.y, acc[1][1]);
            acc[1][2] = fmaf(a.y, b.z, acc[1][2]); acc[1][3] = fmaf(a.y, b.w, acc[1][3]);
            acc[2][0] = fmaf(a.z, b.x, acc[2][0]); acc[2][1] = fmaf(a.z, b.y, acc[2][1]);
            acc[2][2] = fmaf(a.z, b.z, acc[2][2]); acc[2][3] = fmaf(a.z, b.w, acc[2][3]);
            acc[3][0] = fmaf(a.w, b.x, acc[3][0]); acc[3][1] = fmaf(a.w, b.y, acc[3][1]);
            acc[3][2] = fmaf(a.w, b.z, acc[3][2]); acc[3][3] = fmaf(a.w, b.w, acc[3][3]);
        }
        __syncthreads();
    }
    float* pb = partial + (size_t)kc * (OUT_C * OUT_C);
#pragma unroll
    for (int u = 0; u < 4; ++u) {
        float4 v = {acc[u][0], acc[u][1], acc[u][2], acc[u][3]};
        *(float4*)&pb[(c0 + ty * 4 + u) * OUT_C + o0 + tx * 4] = v;
    }
}

// reduce KSPLIT partials + bias -> out (65536 float4 outputs)
__global__ __launch_bounds__(256) void k_readout_reduce(
        const float* __restrict__ partial, const float* __restrict__ br,
        float* __restrict__ out) {
    int i = blockIdx.x * 256 + threadIdx.x;  // float4 index
    const float4* p4 = (const float4*)partial;
    float4 s = p4[i];
#pragma unroll
    for (int k = 1; k < KSPLIT; ++k) {
        float4 t = p4[i + k * 65536];
        s.x += t.x; s.y += t.y; s.z += t.z; s.w += t.w;
    }
    float4 b = ((const float4*)br)[i & 127];
    s.x += b.x; s.y += b.y; s.z += b.z; s.w += b.w;
    ((float4*)out)[i] = s;
}

// ---------------------------------------------------------------------------
extern "C" void kernel_launch(void* const* d_in, const int* in_sizes, int n_in,
                              void* d_out, int out_size, void* d_ws, size_t ws_size,
                              hipStream_t stream) {
    const float* x  = (const float*)d_in[0];
    const int*   ei = (const int*)d_in[1];
    const float* W1 = (const float*)d_in[2];
    const float* b1 = (const float*)d_in[3];
    const float* W2 = (const float*)d_in[4];
    const float* b2 = (const float*)d_in[5];
    const float* W3 = (const float*)d_in[6];
    const float* b3 = (const float*)d_in[7];
    const float* W4 = (const float*)d_in[8];
    const float* b4 = (const float*)d_in[9];
    const float* Wr = (const float*)d_in[10];
    const float* br = (const float*)d_in[11];
    float* out = (float*)d_out;

    // workspace partition (256B-aligned)
    char* ws = (char*)d_ws;
    unsigned int* adj = (unsigned int*)ws;                  // 131072 B
    float* A1 = (float*)(ws + 131072);                      // 262144 B
    float* B1 = (float*)(ws + 393216);                      // 262144 B
    float* A2 = (float*)(ws + 655360);                      // 262144 B
    float* B2 = (float*)(ws + 917504);                      // 262144 B
    float* h2 = (float*)(ws + 1179648);                     // 2097152 B
    unsigned short* Wpk1 = (unsigned short*)(ws + 3276800); // 16384 B
    unsigned short* Wpk2 = (unsigned short*)(ws + 3293184); // 65536 B
    float* partial = (float*)(ws + 3358720);                // 8388608 B (KSPLIT=8 x 1MB)
    // total 11747328 B

    k_init<<<dim3(404), dim3(256), 0, stream>>>(adj, W2, Wpk1, W4, Wpk2,
                                                x, W1, b1, A1, B1);
    k_build_adj<<<dim3(N_EDGES / 256), dim3(256), 0, stream>>>(ei, adj);
    k_conv_mfma<2, HID_C, 8, 4, true><<<dim3(N_NODES), dim3(256), 0, stream>>>(
        adj, A1, B1, Wpk1, b2, nullptr, W3, b3, A2, B2);
    k_conv_mfma<8, OUT_C, 8, 4, false><<<dim3(N_NODES), dim3(256), 0, stream>>>(
        adj, A2, B2, Wpk2, b4, h2, nullptr, nullptr, nullptr, nullptr);
    k_readout_part<<<dim3(64 * KSPLIT), dim3(256), 0, stream>>>(h2, Wr, partial);
    k_readout_reduce<<<dim3(256), dim3(256), 0, stream>>>(partial, br, out);
}